// Round 8
// baseline (1529.957 us; speedup 1.0000x reference)
//
#include <hip/hip_runtime.h>
#include <math.h>

#define TB 256

__device__ __forceinline__ float fast_sigmoid(float x) {
    return 1.0f / (1.0f + __expf(-x));
}
__device__ __forceinline__ float fast_tanh(float x) {
    float a = fabsf(x);
    float e = __expf(2.0f * a);
    float r = 1.0f - 2.0f / (e + 1.0f);
    return copysignf(r, x);
}
__device__ __forceinline__ float gelu_exact(float x) {
    return 0.5f * x * (1.0f + erff(x * 0.70710678118654752f));
}

// ---------------------------------------------------------------------------
// Kernel A (slot_recur3): 512 blocks x 256 threads, one block per batch.
// Setup + P1(conv) + P2(KQV) identical to the verified 809us kernel.
// The 3 attention iterations are restructured wave-per-slot:
//   wave w owns slot w. Per iter:
//     phase A: lanes 0-15 logits (slots_w . kq[n]); lanes 16-63 gh (whh rows
//              e=j, j+48) -- both read the broadcast slot vector.
//              lg written to parity-dbuf lg_s.           [1 barrier]
//     phase B: lanes 0-15 softmax over slots (reads all 4 lg rows);
//              attn broadcast via 16 shfl; gi in regs (e=lane, +64 for
//              lanes<32); one shfl redistributes gi[u+32]; combine lanes 0-31.
// Barriers/step: 5 (was 11). gi_s/attn_s deleted.
// Fused weights (verified rounds 2-7):
//   Mkq[d][dp] = sum_e k_w[e][d] q_w[e][dp]
//   MvW[d][e]  = sum_e' v_w[e'][d] wih[e][e']
//   A12[c][col] = sum_d wts[d][c] * (col<32 ? Mkq[d][col] : MvW[d][col-32])
//   c12[col]    = sum_d bts[d]   * (same)
// ---------------------------------------------------------------------------
__global__ __launch_bounds__(256, 2) void slot_recur3(
    const float* __restrict__ frames, const float* __restrict__ slot_mu,
    const float* __restrict__ conv_w, const float* __restrict__ conv_b,
    const float* __restrict__ to_slot_w, const float* __restrict__ to_slot_b,
    const float* __restrict__ q_w, const float* __restrict__ k_w,
    const float* __restrict__ v_w,
    const float* __restrict__ wih, const float* __restrict__ whh,
    const float* __restrict__ bih, const float* __restrict__ bhh,
    float* __restrict__ slots_out)
{
    const int tid = threadIdx.x;
    const int b = blockIdx.x;
    const int lane = tid & 63;
    const int w = tid >> 6;

    __shared__ float A12_s[32 * 132];
    __shared__ float c12_s[128];
    __shared__ float whh_s[96 * 36];
    __shared__ float vWT_s[96 * 20];
    __shared__ float kq_s[16 * 36];
    __shared__ float X_s[16 * 36];
    __shared__ float feat_s[16 * 36];
    __shared__ float slots_s[4 * 36];
    __shared__ float lg_s[2][80];      // [parity][s*20+n]
    __shared__ float gh_s[4 * 100];    // [s][e]
    __shared__ float bih_s[96], bhh_s[96];
    __shared__ float Mkq_s[1024];
    __shared__ float scr_s[3072];

    // ---- Setup (verbatim from verified kernel) ----
    for (int i = tid; i < 3072; i += 256) A12_s[i] = wih[i];
    for (int i = tid; i < 1024; i += 256) {
        whh_s[i]        = v_w[i];
        whh_s[1024 + i] = k_w[i];
        whh_s[2048 + i] = q_w[i];
        vWT_s[i]        = to_slot_w[i];
    }
    __syncthreads();
    for (int o = tid; o < 1024; o += 256) {
        int d = o >> 5, dp = o & 31;
        float acc = 0.f;
#pragma unroll 8
        for (int e = 0; e < 32; ++e)
            acc += whh_s[1024 + e * 32 + d] * whh_s[2048 + e * 32 + dp];
        Mkq_s[o] = acc;
    }
    for (int o = tid; o < 3072; o += 256) {
        int d = o / 96, e = o - d * 96;
        float acc = 0.f;
#pragma unroll 8
        for (int ep = 0; ep < 32; ++ep)
            acc += whh_s[ep * 32 + d] * A12_s[e * 32 + ep];
        scr_s[d * 96 + e] = acc;
    }
    __syncthreads();
    for (int o = tid; o < 4096; o += 256) {
        int c = o >> 7, col = o & 127;
        float acc = 0.f;
        if (col < 32) {
#pragma unroll 8
            for (int d = 0; d < 32; ++d) acc += vWT_s[d * 32 + c] * Mkq_s[d * 32 + col];
        } else {
            int e = col - 32;
#pragma unroll 8
            for (int d = 0; d < 32; ++d) acc += vWT_s[d * 32 + c] * scr_s[d * 96 + e];
        }
        A12_s[c * 132 + col] = acc;
    }
    if (tid < 128) {
        int col = tid;
        float acc = 0.f;
        if (col < 32) {
            for (int d = 0; d < 32; ++d) acc += to_slot_b[d] * Mkq_s[d * 32 + col];
        } else {
            int e = col - 32;
            for (int d = 0; d < 32; ++d) acc += to_slot_b[d] * scr_s[d * 96 + e];
        }
        c12_s[col] = acc;
    }
    for (int i = tid; i < 3072; i += 256) whh_s[(i >> 5) * 36 + (i & 31)] = whh[i];
    if (tid < 96) { bih_s[tid] = bih[tid]; bhh_s[tid] = bhh[tid]; }
    if (tid < 128) slots_s[(tid >> 5) * 36 + (tid & 31)] = slot_mu[tid];

    const float* fb = frames + (size_t)b * (128 * 256);
    if (tid < 128) {
        int h = tid >> 6, ll = tid & 63;
        int i = ll >> 2, j4 = ll & 3;
        float4 v = *(const float4*)&fb[(h ? 0 : 256) + i * 16 + j4 * 4];
        int n = (i >> 2) * 4 + j4, p = i & 3;
        *(float4*)&X_s[n * 36 + h * 16 + p * 4] = v;
    }
    __syncthreads();

    float* so = slots_out + (size_t)b * (126 * 128);
    int par = 0;

#pragma unroll 1
    for (int t = 0; t < 126; ++t) {
        // ---- P1: conv + gelu -> feat ----
        {
            int o = tid & 31, ng = tid >> 5;
            const float* wv = conv_w + o * 32;
            float acca = conv_b[o], accb = acca;
            const float* xa = &X_s[ng * 36];
            const float* xb = &X_s[(ng + 8) * 36];
#pragma unroll
            for (int k = 0; k < 32; k += 4) {
                float4 w4 = *(const float4*)&wv[k];
                float4 a4 = *(const float4*)&xa[k];
                float4 b4 = *(const float4*)&xb[k];
                acca += w4.x * a4.x + w4.y * a4.y + w4.z * a4.z + w4.w * a4.w;
                accb += w4.x * b4.x + w4.y * b4.y + w4.z * b4.z + w4.w * b4.w;
            }
            feat_s[ng * 36 + o] = gelu_exact(acca);
            feat_s[(ng + 8) * 36 + o] = gelu_exact(accb);
        }
        __syncthreads();   // BAR1

        // ---- P2: KQV GEMM + X(t+1) prefetch ----
        float4 pf;
        const bool havepf = (t < 125) && (tid < 128);
        if (havepf) {
            int h = tid >> 6, ll = tid & 63;
            int i = ll >> 2, j4 = ll & 3;
            pf = *(const float4*)&fb[(t + (h ? 1 : 2)) * 256 + i * 16 + j4 * 4];
        }
        {
            const int cg = tid & 63;
            const int wv = tid >> 6;
            const int col0 = cg * 2;
            float accx[4], accy[4];
#pragma unroll
            for (int j = 0; j < 4; ++j) { accx[j] = 0.f; accy[j] = 0.f; }
#pragma unroll
            for (int c = 0; c < 32; c += 4) {
                float2 a0 = *(const float2*)&A12_s[(c + 0) * 132 + col0];
                float2 a1 = *(const float2*)&A12_s[(c + 1) * 132 + col0];
                float2 a2 = *(const float2*)&A12_s[(c + 2) * 132 + col0];
                float2 a3 = *(const float2*)&A12_s[(c + 3) * 132 + col0];
#pragma unroll
                for (int j = 0; j < 4; ++j) {
                    float4 q = *(const float4*)&feat_s[(wv * 4 + j) * 36 + c];
                    accx[j] += a0.x * q.x + a1.x * q.y + a2.x * q.z + a3.x * q.w;
                    accy[j] += a0.y * q.x + a1.y * q.y + a2.y * q.z + a3.y * q.w;
                }
            }
            float cx = c12_s[col0], cy = c12_s[col0 + 1];
#pragma unroll
            for (int j = 0; j < 4; ++j) {
                int n = wv * 4 + j;
                float vx = accx[j] + cx, vy = accy[j] + cy;
                if (col0 < 32) {
                    *(float2*)&kq_s[n * 36 + col0] = make_float2(vx, vy);
                } else {
                    vWT_s[(col0 - 32) * 20 + n] = vx;
                    vWT_s[(col0 - 31) * 20 + n] = vy;
                }
            }
        }
        if (havepf) {
            int h = tid >> 6, ll = tid & 63;
            int i = ll >> 2, j4 = ll & 3;
            int n = (i >> 2) * 4 + j4, p = i & 3;
            *(float4*)&X_s[n * 36 + h * 16 + p * 4] = pf;
        }
        __syncthreads();   // BAR2

        // ---- 3 attention iterations, wave w owns slot w ----
#pragma unroll 1
        for (int it = 0; it < 3; ++it) {
            // phase A: broadcast slot vector -> regs
            float sr[32];
#pragma unroll
            for (int k = 0; k < 32; k += 4) {
                float4 v = *(const float4*)&slots_s[w * 36 + k];
                sr[k] = v.x; sr[k + 1] = v.y; sr[k + 2] = v.z; sr[k + 3] = v.w;
            }
            if (lane < 16) {
                const float* kr = &kq_s[lane * 36];
                float lg = 0.f;
#pragma unroll
                for (int k = 0; k < 32; k += 4) {
                    float4 kv = *(const float4*)&kr[k];
                    lg += sr[k] * kv.x + sr[k + 1] * kv.y + sr[k + 2] * kv.z + sr[k + 3] * kv.w;
                }
                lg_s[par][w * 20 + lane] = lg * 0.17677669529663687f;  // 1/sqrt(32)
            } else {
                int j = lane - 16;      // e = j and j+48
                const float* w0 = &whh_s[j * 36];
                const float* w1 = &whh_s[(j + 48) * 36];
                float a0 = bhh_s[j], a1 = bhh_s[j + 48];
#pragma unroll
                for (int k = 0; k < 32; k += 4) {
                    float4 w40 = *(const float4*)&w0[k];
                    float4 w41 = *(const float4*)&w1[k];
                    a0 += sr[k] * w40.x + sr[k + 1] * w40.y + sr[k + 2] * w40.z + sr[k + 3] * w40.w;
                    a1 += sr[k] * w41.x + sr[k + 1] * w41.y + sr[k + 2] * w41.z + sr[k + 3] * w41.w;
                }
                gh_s[w * 100 + j] = a0;
                gh_s[w * 100 + j + 48] = a1;
            }
            __syncthreads();   // BAR per iter (lg exchange)

            // phase B
            float attn_val = 0.f;
            if (lane < 16) {
                const float* lp = &lg_s[par][lane];
                float l0 = lp[0], l1 = lp[20], l2 = lp[40], l3 = lp[60];
                float mx = fmaxf(fmaxf(l0, l1), fmaxf(l2, l3));
                float e0 = __expf(l0 - mx), e1 = __expf(l1 - mx);
                float e2 = __expf(l2 - mx), e3 = __expf(l3 - mx);
                float inv = 1.0f / (e0 + e1 + e2 + e3);
                float es = (w == 0) ? e0 : (w == 1) ? e1 : (w == 2) ? e2 : e3;
                attn_val = es * inv;
            }
            float ar[16];
#pragma unroll
            for (int n = 0; n < 16; ++n) ar[n] = __shfl(attn_val, n);

            // gi for e = lane (all 64), e = lane+64 (lanes<32)
            float gA;
            {
                const float* vr = &vWT_s[lane * 20];
                float acc = bih_s[lane];
#pragma unroll
                for (int n = 0; n < 16; n += 4) {
                    float4 v4 = *(const float4*)&vr[n];
                    acc += ar[n] * v4.x + ar[n + 1] * v4.y + ar[n + 2] * v4.z + ar[n + 3] * v4.w;
                }
                gA = acc;
            }
            float gB = 0.f;
            if (lane < 32) {
                const float* vr = &vWT_s[(lane + 64) * 20];
                float acc = bih_s[lane + 64];
#pragma unroll
                for (int n = 0; n < 16; n += 4) {
                    float4 v4 = *(const float4*)&vr[n];
                    acc += ar[n] * v4.x + ar[n + 1] * v4.y + ar[n + 2] * v4.z + ar[n + 3] * v4.w;
                }
                gB = acc;
            }
            float giz = __shfl(gA, lane + 32);
            if (lane < 32) {
                float ghr = gh_s[w * 100 + lane];
                float ghz = gh_s[w * 100 + 32 + lane];
                float ghn = gh_s[w * 100 + 64 + lane];
                float h = slots_s[w * 36 + lane];
                float r = fast_sigmoid(gA + ghr);
                float z = fast_sigmoid(giz + ghz);
                float nn = fast_tanh(gB + r * ghn);
                float hn = (1.f - z) * nn + z * h;
                slots_s[w * 36 + lane] = hn;
                if (it == 2) so[t * 128 + w * 32 + lane] = hn;
            }
            __builtin_amdgcn_wave_barrier();  // order slots write vs next-iter read
            par ^= 1;
        }
    }
}

// ---------------------------------------------------------------------------
// Kernel B (decode2): GEMM (64512 x 512) = slots_traj @ dec_w^T with 8x8
// register tiles. 32 rows/block; dec_w streamed in k-panels [512 cols][16 k]
// (stride 20, conflict-lite); slot-row reads are wave-uniform broadcasts
// (wave = row-group). Epilogue (deconv+tanh+clip) unchanged (verified).
// ---------------------------------------------------------------------------
__global__ __launch_bounds__(TB, 1) void decode2(
    const float* __restrict__ slots_traj, const float* __restrict__ frames,
    const float* __restrict__ dec_w, const float* __restrict__ dec_b,
    const float* __restrict__ deconv_w, const float* __restrict__ deconv_b,
    float* __restrict__ out)
{
    const int tid = threadIdx.x;
    const int m0 = blockIdx.x * 32;
    const int cg = tid & 63;   // col thread: cols cg + 64*m
    const int rg = tid >> 6;   // wave = row group: rows rg*8 + r

    __shared__ float slb[32 * 132];
    __shared__ float wpan[512 * 20];   // k-panel [col][16k + pad4]
    __shared__ float dw_s[512];
    __shared__ float db_s[512];

    for (int i = tid * 4; i < 32 * 128; i += TB * 4) {
        float4 v = *(const float4*)&slots_traj[(size_t)m0 * 128 + i];
        int r = i >> 7, k = i & 127;
        *(float4*)&slb[r * 132 + k] = v;
    }
    for (int i = tid; i < 512; i += TB) {
        dw_s[i] = deconv_w[i];
        db_s[i] = dec_b[i];
    }

    // panel-0 prefetch: thread covers (cbase + 64*pp, quad q)
    const int q = tid & 3, cbase = tid >> 2;
    const float4* dw4 = (const float4*)dec_w;
    float4 pf[8];
#pragma unroll
    for (int pp = 0; pp < 8; ++pp)
        pf[pp] = dw4[(cbase + 64 * pp) * 32 + q];
    __syncthreads();

    float acc[8][8];
#pragma unroll
    for (int m = 0; m < 8; ++m)
#pragma unroll
        for (int r = 0; r < 8; ++r) acc[m][r] = 0.f;

#pragma unroll 1
    for (int p = 0; p < 8; ++p) {
        // write prefetched panel to LDS
#pragma unroll
        for (int pp = 0; pp < 8; ++pp)
            *(float4*)&wpan[(cbase + 64 * pp) * 20 + q * 4] = pf[pp];
        if (p < 7) {
#pragma unroll
            for (int pp = 0; pp < 8; ++pp)
                pf[pp] = dw4[(cbase + 64 * pp) * 32 + (p + 1) * 4 + q];
        }
        __syncthreads();

#pragma unroll
        for (int kq = 0; kq < 4; ++kq) {
            const int kk = p * 16 + kq * 4;
            float4 s4[8];
#pragma unroll
            for (int r = 0; r < 8; ++r)
                s4[r] = *(const float4*)&slb[(rg * 8 + r) * 132 + kk];
#pragma unroll
            for (int m = 0; m < 8; ++m) {
                float4 w4 = *(const float4*)&wpan[(cg + 64 * m) * 20 + kq * 4];
#pragma unroll
                for (int r = 0; r < 8; ++r)
                    acc[m][r] += w4.x * s4[r].x + w4.y * s4[r].y +
                                 w4.z * s4[r].z + w4.w * s4[r].w;
            }
        }
        if (p < 7) __syncthreads();
    }

    // bias
#pragma unroll
    for (int m = 0; m < 8; ++m) {
        float bo = db_s[cg + 64 * m];
#pragma unroll
        for (int r = 0; r < 8; ++r) acc[m][r] += bo;
    }

    // epilogue: deconv + tanh + add curr + clip (verified mapping)
    const int c0 = cg >> 4;
    const int sp = cg & 15;
    const int bi = sp >> 2, bj = sp & 3;
    const float db0 = deconv_b[0];

#pragma unroll 1
    for (int rr = 0; rr < 8; ++rr) {
        float part[16];
#pragma unroll
        for (int kl = 0; kl < 16; ++kl) part[kl] = 0.f;
#pragma unroll
        for (int m = 0; m < 8; ++m) {
            float sf = acc[m][rr];
            const float* dwp = &dw_s[(c0 + 4 * m) * 16];
#pragma unroll
            for (int kl = 0; kl < 16; ++kl) part[kl] += sf * dwp[kl];
        }
#pragma unroll
        for (int kl = 0; kl < 16; ++kl) {
            part[kl] += __shfl_xor(part[kl], 16);
            part[kl] += __shfl_xor(part[kl], 32);
        }
        if (c0 == 0) {
            int mrow = m0 + rg * 8 + rr;
            int bb = mrow / 126, tt = mrow - bb * 126;
            const float* fr = frames + ((size_t)bb * 128 + (tt + 1)) * 256;
            float* op = out + (size_t)mrow * 256;
#pragma unroll
            for (int kk = 0; kk < 4; ++kk) {
                int pixb = (bi * 4 + kk) * 16 + bj * 4;
                float4 c4 = *(const float4*)&fr[pixb];
                float4 o4;
                o4.x = fminf(fmaxf(c4.x + tanhf(part[kk * 4 + 0] + db0), 0.f), 1.f);
                o4.y = fminf(fmaxf(c4.y + tanhf(part[kk * 4 + 1] + db0), 0.f), 1.f);
                o4.z = fminf(fmaxf(c4.z + tanhf(part[kk * 4 + 2] + db0), 0.f), 1.f);
                o4.w = fminf(fmaxf(c4.w + tanhf(part[kk * 4 + 3] + db0), 0.f), 1.f);
                *(float4*)&op[pixb] = o4;
            }
        }
    }
}

extern "C" void kernel_launch(void* const* d_in, const int* in_sizes, int n_in,
                              void* d_out, int out_size, void* d_ws, size_t ws_size,
                              hipStream_t stream) {
    const float* frames    = (const float*)d_in[0];
    const float* slot_mu   = (const float*)d_in[1];
    const float* conv_w    = (const float*)d_in[2];
    const float* conv_b    = (const float*)d_in[3];
    const float* to_slot_w = (const float*)d_in[4];
    const float* to_slot_b = (const float*)d_in[5];
    const float* q_w       = (const float*)d_in[6];
    const float* k_w       = (const float*)d_in[7];
    const float* v_w       = (const float*)d_in[8];
    const float* gru_wih   = (const float*)d_in[9];
    const float* gru_whh   = (const float*)d_in[10];
    const float* gru_bih   = (const float*)d_in[11];
    const float* gru_bhh   = (const float*)d_in[12];
    const float* dec_w     = (const float*)d_in[13];
    const float* dec_b     = (const float*)d_in[14];
    const float* deconv_w  = (const float*)d_in[15];
    const float* deconv_b  = (const float*)d_in[16];

    float* slots_traj = (float*)d_ws;  // 512*126*128 floats = 33 MB
    float* outp = (float*)d_out;

    hipLaunchKernelGGL(slot_recur3, dim3(512), dim3(256), 0, stream,
                       frames, slot_mu, conv_w, conv_b, to_slot_w, to_slot_b,
                       q_w, k_w, v_w, gru_wih, gru_whh, gru_bih, gru_bhh,
                       slots_traj);
    hipLaunchKernelGGL(decode2, dim3(64512 / 32), dim3(TB), 0, stream,
                       slots_traj, frames, dec_w, dec_b, deconv_w, deconv_b,
                       outp);
}

// Round 9
// 1031.624 us; speedup vs baseline: 1.4831x; 1.4831x over previous
//
#include <hip/hip_runtime.h>
#include <math.h>

#define TB 256

__device__ __forceinline__ float fast_sigmoid(float x) {
    return 1.0f / (1.0f + __expf(-x));
}
__device__ __forceinline__ float fast_tanh(float x) {
    float a = fabsf(x);
    float e = __expf(2.0f * a);
    float r = 1.0f - 2.0f / (e + 1.0f);
    return copysignf(r, x);
}
// tanh-form GELU: max |err| vs exact ~3e-4, far below the 2e-2 threshold
__device__ __forceinline__ float fast_gelu(float x) {
    float x3 = x * x * x;
    return 0.5f * x * (1.0f + fast_tanh(0.7978845608028654f * (x + 0.044715f * x3)));
}

// ---------------------------------------------------------------------------
// Kernel A: verified round-2 structure (809 us) with two deltas:
//  (1) gi + GRU-combine merged into one phase (8 barriers/step, was 11);
//      gi_s deleted -- thread (s,d) computes gi[d], gi[d+32], gi[d+64] itself.
//  (2) tanh-form GELU (erff removed).
// One block per batch element, 256 threads, 2 blocks/CU.
// Fused weights (verified rounds 2-8):
//   Mkq[d][dp] = sum_e k_w[e][d] q_w[e][dp]
//   MvW[d][e]  = sum_e' v_w[e'][d] wih[e][e']
//   A12[c][col] = sum_d wts[d][c] * (col<32 ? Mkq[d][col] : MvW[d][col-32])
//   c12[col]    = sum_d bts[d]   * (same)
// Per step: P1 conv+gelu | P2 KQV GEMM + X(t+1) prefetch |
//   3x { [wave0: logits+shfl-softmax -> attn_s || waves1-3: gh -> gh_s] |
//        [tid<128: gi (3 dots, reg) + GRU combine -> slots_s(+traj)] }
// ---------------------------------------------------------------------------
__global__ __launch_bounds__(256, 2) void slot_recur_kernel(
    const float* __restrict__ frames, const float* __restrict__ slot_mu,
    const float* __restrict__ conv_w, const float* __restrict__ conv_b,
    const float* __restrict__ to_slot_w, const float* __restrict__ to_slot_b,
    const float* __restrict__ q_w, const float* __restrict__ k_w,
    const float* __restrict__ v_w,
    const float* __restrict__ wih, const float* __restrict__ whh,
    const float* __restrict__ bih, const float* __restrict__ bhh,
    float* __restrict__ slots_out)
{
    const int tid = threadIdx.x;
    const int b = blockIdx.x;
    const int lane = tid & 63;
    const int wid = tid >> 6;

    __shared__ float A12_s[32 * 132];
    __shared__ float c12_s[128];
    __shared__ float whh_s[96 * 36];
    __shared__ float vWT_s[96 * 20];
    __shared__ float kq_s[16 * 36];
    __shared__ float X_s[16 * 36];
    __shared__ float feat_s[16 * 36];
    __shared__ float slots_s[4 * 36];
    __shared__ float attn_s[4 * 20];
    __shared__ float bih_s[96], bhh_s[96];
    __shared__ float Mkq_s[1024];
    __shared__ float scr_s[32 * 96];
    __shared__ float gh_s[4 * 100];

    // ---- Setup (verbatim from verified 809us kernel) ----
    for (int i = tid; i < 3072; i += 256) A12_s[i] = wih[i];
    for (int i = tid; i < 1024; i += 256) {
        whh_s[i]        = v_w[i];
        whh_s[1024 + i] = k_w[i];
        whh_s[2048 + i] = q_w[i];
        vWT_s[i]        = to_slot_w[i];
    }
    __syncthreads();
    for (int o = tid; o < 1024; o += 256) {
        int d = o >> 5, dp = o & 31;
        float acc = 0.f;
#pragma unroll 8
        for (int e = 0; e < 32; ++e)
            acc += whh_s[1024 + e * 32 + d] * whh_s[2048 + e * 32 + dp];
        Mkq_s[o] = acc;
    }
    for (int o = tid; o < 3072; o += 256) {
        int d = o / 96, e = o - d * 96;
        float acc = 0.f;
#pragma unroll 8
        for (int ep = 0; ep < 32; ++ep)
            acc += whh_s[ep * 32 + d] * A12_s[e * 32 + ep];
        scr_s[d * 96 + e] = acc;
    }
    __syncthreads();
    for (int o = tid; o < 4096; o += 256) {
        int c = o >> 7, col = o & 127;
        float acc = 0.f;
        if (col < 32) {
#pragma unroll 8
            for (int d = 0; d < 32; ++d) acc += vWT_s[d * 32 + c] * Mkq_s[d * 32 + col];
        } else {
            int e = col - 32;
#pragma unroll 8
            for (int d = 0; d < 32; ++d) acc += vWT_s[d * 32 + c] * scr_s[d * 96 + e];
        }
        A12_s[c * 132 + col] = acc;
    }
    if (tid < 128) {
        int col = tid;
        float acc = 0.f;
        if (col < 32) {
            for (int d = 0; d < 32; ++d) acc += to_slot_b[d] * Mkq_s[d * 32 + col];
        } else {
            int e = col - 32;
            for (int d = 0; d < 32; ++d) acc += to_slot_b[d] * scr_s[d * 96 + e];
        }
        c12_s[col] = acc;
    }
    for (int i = tid; i < 3072; i += 256) whh_s[(i >> 5) * 36 + (i & 31)] = whh[i];
    if (tid < 96) { bih_s[tid] = bih[tid]; bhh_s[tid] = bhh[tid]; }
    if (tid < 128) slots_s[(tid >> 5) * 36 + (tid & 31)] = slot_mu[tid];

    const float* fb = frames + (size_t)b * (128 * 256);
    if (tid < 128) {
        int h = tid >> 6, ll = tid & 63;
        int i = ll >> 2, j4 = ll & 3;
        float4 v = *(const float4*)&fb[(h ? 0 : 256) + i * 16 + j4 * 4];
        int n = (i >> 2) * 4 + j4, p = i & 3;
        *(float4*)&X_s[n * 36 + h * 16 + p * 4] = v;
    }
    __syncthreads();

    float* so = slots_out + (size_t)b * (126 * 128);

#pragma unroll 1
    for (int t = 0; t < 126; ++t) {
        // ---- P1: conv + gelu -> feat (verbatim except fast_gelu) ----
        {
            int o = tid & 31, ng = tid >> 5;
            const float* w = conv_w + o * 32;
            float acca = conv_b[o], accb = acca;
            const float* xa = &X_s[ng * 36];
            const float* xb = &X_s[(ng + 8) * 36];
#pragma unroll
            for (int k = 0; k < 32; k += 4) {
                float4 w4 = *(const float4*)&w[k];
                float4 a4 = *(const float4*)&xa[k];
                float4 b4 = *(const float4*)&xb[k];
                acca += w4.x * a4.x + w4.y * a4.y + w4.z * a4.z + w4.w * a4.w;
                accb += w4.x * b4.x + w4.y * b4.y + w4.z * b4.z + w4.w * b4.w;
            }
            feat_s[ng * 36 + o] = fast_gelu(acca);
            feat_s[(ng + 8) * 36 + o] = fast_gelu(accb);
        }
        __syncthreads();   // BAR 1

        // ---- P2: KQV GEMM + X(t+1) prefetch (verbatim) ----
        float4 pf;
        const bool havepf = (t < 125) && (tid < 128);
        if (havepf) {
            int h = tid >> 6, ll = tid & 63;
            int i = ll >> 2, j4 = ll & 3;
            pf = *(const float4*)&fb[(t + (h ? 1 : 2)) * 256 + i * 16 + j4 * 4];
        }
        {
            const int cg = tid & 63;
            const int wv = tid >> 6;
            const int col0 = cg * 2;
            float accx[4], accy[4];
#pragma unroll
            for (int j = 0; j < 4; ++j) { accx[j] = 0.f; accy[j] = 0.f; }
#pragma unroll
            for (int c = 0; c < 32; c += 4) {
                float2 a0 = *(const float2*)&A12_s[(c + 0) * 132 + col0];
                float2 a1 = *(const float2*)&A12_s[(c + 1) * 132 + col0];
                float2 a2 = *(const float2*)&A12_s[(c + 2) * 132 + col0];
                float2 a3 = *(const float2*)&A12_s[(c + 3) * 132 + col0];
#pragma unroll
                for (int j = 0; j < 4; ++j) {
                    float4 q = *(const float4*)&feat_s[(wv * 4 + j) * 36 + c];
                    accx[j] += a0.x * q.x + a1.x * q.y + a2.x * q.z + a3.x * q.w;
                    accy[j] += a0.y * q.x + a1.y * q.y + a2.y * q.z + a3.y * q.w;
                }
            }
            float cx = c12_s[col0], cy = c12_s[col0 + 1];
#pragma unroll
            for (int j = 0; j < 4; ++j) {
                int n = wv * 4 + j;
                float vx = accx[j] + cx, vy = accy[j] + cy;
                if (col0 < 32) {
                    *(float2*)&kq_s[n * 36 + col0] = make_float2(vx, vy);
                } else {
                    vWT_s[(col0 - 32) * 20 + n] = vx;
                    vWT_s[(col0 - 31) * 20 + n] = vy;
                }
            }
        }
        if (havepf) {
            int h = tid >> 6, ll = tid & 63;
            int i = ll >> 2, j4 = ll & 3;
            int n = (i >> 2) * 4 + j4, p = i & 3;
            *(float4*)&X_s[n * 36 + h * 16 + p * 4] = pf;
        }
        __syncthreads();   // BAR 2

        // ---- 3 attention iterations, 2 barriers each ----
#pragma unroll 1
        for (int it = 0; it < 3; ++it) {
            // phase A: wave0 logits + shfl-softmax ; waves1-3 gh
            if (wid == 0) {
                int s = lane >> 4, n = lane & 15;
                const float* sp = &slots_s[s * 36];
                const float* kp = &kq_s[n * 36];
                float acc = 0.f;
#pragma unroll
                for (int d = 0; d < 32; d += 4) {
                    float4 a = *(const float4*)&sp[d];
                    float4 c = *(const float4*)&kp[d];
                    acc += a.x * c.x + a.y * c.y + a.z * c.z + a.w * c.w;
                }
                float lg = acc * 0.17677669529663687f;  // 1/sqrt(32)
                float m = fmaxf(lg, __shfl_xor(lg, 16));
                m = fmaxf(m, __shfl_xor(m, 32));
                float e = __expf(lg - m);
                float ssum = e + __shfl_xor(e, 16);
                ssum += __shfl_xor(ssum, 32);
                attn_s[s * 20 + n] = e / ssum;
            } else {
                int idx = tid - 64;
                int shh = idx / 96;
                int e = idx - shh * 96;
                int s0 = shh * 2;
                const float* w = &whh_s[e * 36];
                const float* sa = &slots_s[s0 * 36];
                const float* sb = &slots_s[(s0 + 1) * 36];
                float acc0 = bhh_s[e], acc1 = acc0;
#pragma unroll
                for (int d = 0; d < 32; d += 4) {
                    float4 w4 = *(const float4*)&w[d];
                    float4 a4 = *(const float4*)&sa[d];
                    float4 b4 = *(const float4*)&sb[d];
                    acc0 += w4.x * a4.x + w4.y * a4.y + w4.z * a4.z + w4.w * a4.w;
                    acc1 += w4.x * b4.x + w4.y * b4.y + w4.z * b4.z + w4.w * b4.w;
                }
                gh_s[s0 * 100 + e] = acc0;
                gh_s[(s0 + 1) * 100 + e] = acc1;
            }
            __syncthreads();   // BAR A->B

            // phase B (merged gi + GRU combine): tid<128, (s,d)
            if (tid < 128) {
                int s = tid >> 5, d = tid & 31;
                float ar[16];
#pragma unroll
                for (int k = 0; k < 16; k += 4) {
                    float4 a4 = *(const float4*)&attn_s[s * 20 + k];
                    ar[k] = a4.x; ar[k + 1] = a4.y; ar[k + 2] = a4.z; ar[k + 3] = a4.w;
                }
                const float* v0 = &vWT_s[d * 20];
                const float* v1 = &vWT_s[(d + 32) * 20];
                const float* v2 = &vWT_s[(d + 64) * 20];
                float gir = bih_s[d], giz = bih_s[32 + d], gin = bih_s[64 + d];
#pragma unroll
                for (int n = 0; n < 16; n += 4) {
                    float4 x0 = *(const float4*)&v0[n];
                    float4 x1 = *(const float4*)&v1[n];
                    float4 x2 = *(const float4*)&v2[n];
                    gir += ar[n] * x0.x + ar[n + 1] * x0.y + ar[n + 2] * x0.z + ar[n + 3] * x0.w;
                    giz += ar[n] * x1.x + ar[n + 1] * x1.y + ar[n + 2] * x1.z + ar[n + 3] * x1.w;
                    gin += ar[n] * x2.x + ar[n + 1] * x2.y + ar[n + 2] * x2.z + ar[n + 3] * x2.w;
                }
                float ghr = gh_s[s * 100 + d];
                float ghz = gh_s[s * 100 + 32 + d];
                float ghn = gh_s[s * 100 + 64 + d];
                float r = fast_sigmoid(gir + ghr);
                float z = fast_sigmoid(giz + ghz);
                float nn = fast_tanh(gin + r * ghn);
                float h = slots_s[s * 36 + d];
                float hn = (1.0f - z) * nn + z * h;
                slots_s[s * 36 + d] = hn;
                if (it == 2) so[t * 128 + tid] = hn;
            }
            __syncthreads();   // BAR B->next A
        }
    }
}

// ---------------------------------------------------------------------------
// Kernel B: batched decode (byte-identical to the verified ~223us version).
// GEMM (64512 x 512) = slots_traj (64512 x 128) @ dec_w^T, fused
// deconv(4x4,s4) + tanh + add curr + clip. 32 rows per block.
// ---------------------------------------------------------------------------
__global__ __launch_bounds__(TB, 1) void decode_kernel(
    const float* __restrict__ slots_traj, const float* __restrict__ frames,
    const float* __restrict__ dec_w, const float* __restrict__ dec_b,
    const float* __restrict__ deconv_w, const float* __restrict__ deconv_b,
    float* __restrict__ out)
{
    const int tid = threadIdx.x;
    const int m0 = blockIdx.x * 32;

    __shared__ float sl_s[32 * 132];
    __shared__ float wch_s[64 * 132];
    __shared__ float dw_s[512];
    __shared__ float db_s[512];

    for (int i = tid * 4; i < 32 * 128; i += TB * 4) {
        float4 v = *(const float4*)&slots_traj[(size_t)m0 * 128 + i];
        int r = i >> 7, k = i & 127;
        *(float4*)&sl_s[r * 132 + k] = v;
    }
    for (int i = tid; i < 512; i += TB) {
        dw_s[i] = deconv_w[i];
        db_s[i] = dec_b[i];
    }
    __syncthreads();

    const int cg = tid & 63;
    const int rg = tid >> 6;

    float acc[8][8];
#pragma unroll
    for (int ci = 0; ci < 8; ++ci)
#pragma unroll
        for (int rr = 0; rr < 8; ++rr) acc[ci][rr] = 0.f;

    const float* slb = &sl_s[(rg * 8) * 132];

#pragma unroll
    for (int ch = 0; ch < 8; ++ch) {
        for (int i = tid * 4; i < 64 * 128; i += TB * 4) {
            float4 v = *(const float4*)&dec_w[(size_t)ch * 8192 + i];
            int cl = i >> 7, k = i & 127;
            *(float4*)&wch_s[cl * 132 + k] = v;
        }
        __syncthreads();
        const float* wrow = &wch_s[cg * 132];
#pragma unroll 4
        for (int k = 0; k < 128; k += 4) {
            float4 w4 = *(const float4*)&wrow[k];
#pragma unroll
            for (int rr = 0; rr < 8; ++rr) {
                float4 s4 = *(const float4*)&slb[rr * 132 + k];
                acc[ch][rr] += w4.x * s4.x + w4.y * s4.y + w4.z * s4.z + w4.w * s4.w;
            }
        }
        __syncthreads();
    }

#pragma unroll
    for (int ci = 0; ci < 8; ++ci) {
        float bo = db_s[cg + 64 * ci];
#pragma unroll
        for (int rr = 0; rr < 8; ++rr) acc[ci][rr] += bo;
    }

    const int c0 = cg >> 4;
    const int sp = cg & 15;
    const int bi = sp >> 2, bj = sp & 3;
    const float db0 = deconv_b[0];

#pragma unroll 1
    for (int rr = 0; rr < 8; ++rr) {
        float part[16];
#pragma unroll
        for (int kl = 0; kl < 16; ++kl) part[kl] = 0.f;
#pragma unroll
        for (int m = 0; m < 8; ++m) {
            float sf = acc[m][rr];
            const float* dwp = &dw_s[(c0 + 4 * m) * 16];
#pragma unroll
            for (int kl = 0; kl < 16; ++kl) part[kl] += sf * dwp[kl];
        }
#pragma unroll
        for (int kl = 0; kl < 16; ++kl) {
            part[kl] += __shfl_xor(part[kl], 16);
            part[kl] += __shfl_xor(part[kl], 32);
        }
        if (c0 == 0) {
            int mrow = m0 + rg * 8 + rr;
            int bb = mrow / 126, tt = mrow - bb * 126;
            const float* fr = frames + ((size_t)bb * 128 + (tt + 1)) * 256;
            float* op = out + (size_t)mrow * 256;
#pragma unroll
            for (int kk = 0; kk < 4; ++kk) {
                int pixb = (bi * 4 + kk) * 16 + bj * 4;
                float4 c4 = *(const float4*)&fr[pixb];
                float4 o4;
                o4.x = fminf(fmaxf(c4.x + tanhf(part[kk * 4 + 0] + db0), 0.f), 1.f);
                o4.y = fminf(fmaxf(c4.y + tanhf(part[kk * 4 + 1] + db0), 0.f), 1.f);
                o4.z = fminf(fmaxf(c4.z + tanhf(part[kk * 4 + 2] + db0), 0.f), 1.f);
                o4.w = fminf(fmaxf(c4.w + tanhf(part[kk * 4 + 3] + db0), 0.f), 1.f);
                *(float4*)&op[pixb] = o4;
            }
        }
    }
}

extern "C" void kernel_launch(void* const* d_in, const int* in_sizes, int n_in,
                              void* d_out, int out_size, void* d_ws, size_t ws_size,
                              hipStream_t stream) {
    const float* frames    = (const float*)d_in[0];
    const float* slot_mu   = (const float*)d_in[1];
    const float* conv_w    = (const float*)d_in[2];
    const float* conv_b    = (const float*)d_in[3];
    const float* to_slot_w = (const float*)d_in[4];
    const float* to_slot_b = (const float*)d_in[5];
    const float* q_w       = (const float*)d_in[6];
    const float* k_w       = (const float*)d_in[7];
    const float* v_w       = (const float*)d_in[8];
    const float* gru_wih   = (const float*)d_in[9];
    const float* gru_whh   = (const float*)d_in[10];
    const float* gru_bih   = (const float*)d_in[11];
    const float* gru_bhh   = (const float*)d_in[12];
    const float* dec_w     = (const float*)d_in[13];
    const float* dec_b     = (const float*)d_in[14];
    const float* deconv_w  = (const float*)d_in[15];
    const float* deconv_b  = (const float*)d_in[16];

    float* slots_traj = (float*)d_ws;  // 512*126*128 floats = 33 MB
    float* outp = (float*)d_out;

    hipLaunchKernelGGL(slot_recur_kernel, dim3(512), dim3(256), 0, stream,
                       frames, slot_mu, conv_w, conv_b, to_slot_w, to_slot_b,
                       q_w, k_w, v_w, gru_wih, gru_whh, gru_bih, gru_bhh,
                       slots_traj);
    hipLaunchKernelGGL(decode_kernel, dim3(64512 / 32), dim3(TB), 0, stream,
                       slots_traj, frames, dec_w, dec_b, deconv_w, deconv_b,
                       outp);
}

// Round 10
// 1027.643 us; speedup vs baseline: 1.4888x; 1.0039x over previous
//
#include <hip/hip_runtime.h>
#include <math.h>

#define TB 256

__device__ __forceinline__ float fast_sigmoid(float x) {
    return 1.0f / (1.0f + __expf(-x));
}
__device__ __forceinline__ float fast_tanh(float x) {
    float a = fabsf(x);
    float e = __expf(2.0f * a);
    float r = 1.0f - 2.0f / (e + 1.0f);
    return copysignf(r, x);
}
// tanh-form GELU: max |err| vs exact ~3e-4, far below the 2e-2 threshold
__device__ __forceinline__ float fast_gelu(float x) {
    float x3 = x * x * x;
    return 0.5f * x * (1.0f + fast_tanh(0.7978845608028654f * (x + 0.044715f * x3)));
}

// ---------------------------------------------------------------------------
// LDS pool (floats). 12144 floats = 48.6 KB -> 3 blocks/CU (was 65.5 KB -> 2).
// Setup temps alias runtime regions, each consumed before its runtime use:
//   staged wih   -> P_A12   (consumed by S1b, overwritten by S2)
//   staged v/k/q -> P_WHH   (k,q consumed by S1a; v by S1b; real whh at S3)
//   staged wts   -> P_VWT   (consumed by S2; overwritten at runtime P2)
//   Mkq          -> P_KQ..  (1024, spans kq+X; consumed by S2; X written S3)
//   MvW          -> split: [0,2432) at P_WHH+1024 ; [2432,3072) at P_FEAT..
// ---------------------------------------------------------------------------
#define P_A12   0        // 4096 : A12 [c][col] stride 128
#define P_C12   4096     // 128
#define P_WHH   4224     // 3456 : whh [e][d] stride 36
#define P_VWT   7680     // 1920 : vWT [e][n] stride 20
#define P_KQ    9600     // 576  : kq  [n][d] stride 36
#define P_X     10176    // 576  : X   [n][k] stride 36
#define P_FEAT  10752    // 576  : feat[n][c] stride 36
#define P_SLOTS 11328    // 144  : slots [s][d] stride 36
#define P_ATTN  11472    // 80   : attn [s][n] stride 20
#define P_GH    11552    // 400  : gh [s][e] stride 100
#define P_BIH   11952    // 96
#define P_BHH   12048    // 96
#define P_SZ    12144

// ---------------------------------------------------------------------------
// Kernel A: round-9 algorithm (verified 806us), LDS-dieted for 3 blocks/CU.
// One block per batch element, 256 threads. Per step: P1 conv+gelu | P2 KQV
// GEMM + X(t+1) prefetch | 3x { [wave0 logits+shfl-softmax || waves1-3 gh] |
// [tid<128: gi(3 dots)+GRU combine] }.
// Fused weights (verified rounds 2-9):
//   Mkq[d][dp] = sum_e k_w[e][d] q_w[e][dp]
//   MvW[d][e]  = sum_e' v_w[e'][d] wih[e][e']
//   A12[c][col] = sum_d wts[d][c] * (col<32 ? Mkq[d][col] : MvW[d][col-32])
//   c12[col]    = sum_d bts[d]   * (same)
// ---------------------------------------------------------------------------
__global__ __launch_bounds__(256, 2) void slot_recur_kernel(
    const float* __restrict__ frames, const float* __restrict__ slot_mu,
    const float* __restrict__ conv_w, const float* __restrict__ conv_b,
    const float* __restrict__ to_slot_w, const float* __restrict__ to_slot_b,
    const float* __restrict__ q_w, const float* __restrict__ k_w,
    const float* __restrict__ v_w,
    const float* __restrict__ wih, const float* __restrict__ whh,
    const float* __restrict__ bih, const float* __restrict__ bhh,
    float* __restrict__ slots_out)
{
    const int tid = threadIdx.x;
    const int b = blockIdx.x;
    const int lane = tid & 63;
    const int wid = tid >> 6;

    __shared__ float pool[P_SZ];

    // ---- S0: stage raw weights into aliased regions ----
    for (int i = tid; i < 3072; i += 256) pool[P_A12 + i] = wih[i];
    for (int i = tid; i < 1024; i += 256) {
        pool[P_WHH + i]        = v_w[i];
        pool[P_WHH + 1024 + i] = k_w[i];
        pool[P_WHH + 2048 + i] = q_w[i];
        pool[P_VWT + i]        = to_slot_w[i];
    }
    __syncthreads();

    // ---- S1a: Mkq -> pool[P_KQ..P_KQ+1024) (reads staged k,q) ----
    for (int o = tid; o < 1024; o += 256) {
        int d = o >> 5, dp = o & 31;
        float acc = 0.f;
#pragma unroll 8
        for (int e = 0; e < 32; ++e)
            acc += pool[P_WHH + 1024 + e * 32 + d] * pool[P_WHH + 2048 + e * 32 + dp];
        pool[P_KQ + o] = acc;
    }
    __syncthreads();

    // ---- S1b: MvW (reads staged v @WHH[0:1024), wih @A12) -> split store ----
    for (int o = tid; o < 3072; o += 256) {
        int d = o / 96, e = o - d * 96;
        float acc = 0.f;
#pragma unroll 8
        for (int ep = 0; ep < 32; ++ep)
            acc += pool[P_WHH + ep * 32 + d] * pool[P_A12 + e * 32 + ep];
        if (o < 2432) pool[P_WHH + 1024 + o] = acc;
        else          pool[P_FEAT + o - 2432] = acc;
    }
    __syncthreads();

    // ---- S2: A12/c12 (reads staged wts @VWT, Mkq, MvW) ----
    for (int o = tid; o < 4096; o += 256) {
        int c = o >> 7, col = o & 127;
        float acc = 0.f;
        if (col < 32) {
#pragma unroll 8
            for (int d = 0; d < 32; ++d)
                acc += pool[P_VWT + d * 32 + c] * pool[P_KQ + d * 32 + col];
        } else {
            int e = col - 32;
#pragma unroll 8
            for (int d = 0; d < 32; ++d) {
                int i = d * 96 + e;
                float mv = (i < 2432) ? pool[P_WHH + 1024 + i] : pool[P_FEAT + i - 2432];
                acc += pool[P_VWT + d * 32 + c] * mv;
            }
        }
        pool[P_A12 + c * 128 + col] = acc;
    }
    if (tid < 128) {
        int col = tid;
        float acc = 0.f;
        if (col < 32) {
            for (int d = 0; d < 32; ++d)
                acc += to_slot_b[d] * pool[P_KQ + d * 32 + col];
        } else {
            int e = col - 32;
            for (int d = 0; d < 32; ++d) {
                int i = d * 96 + e;
                float mv = (i < 2432) ? pool[P_WHH + 1024 + i] : pool[P_FEAT + i - 2432];
                acc += to_slot_b[d] * mv;
            }
        }
        pool[P_C12 + col] = acc;
    }
    __syncthreads();

    // ---- S3: real whh (strided), biases, slots init, X(t=0) ----
    for (int i = tid; i < 3072; i += 256)
        pool[P_WHH + (i >> 5) * 36 + (i & 31)] = whh[i];
    if (tid < 96) { pool[P_BIH + tid] = bih[tid]; pool[P_BHH + tid] = bhh[tid]; }
    if (tid < 128)
        pool[P_SLOTS + (tid >> 5) * 36 + (tid & 31)] = slot_mu[tid];

    const float* fb = frames + (size_t)b * (128 * 256);
    if (tid < 128) {
        int h = tid >> 6, ll = tid & 63;
        int i = ll >> 2, j4 = ll & 3;
        float4 v = *(const float4*)&fb[(h ? 0 : 256) + i * 16 + j4 * 4];
        int n = (i >> 2) * 4 + j4, p = i & 3;
        *(float4*)&pool[P_X + n * 36 + h * 16 + p * 4] = v;
    }
    __syncthreads();

    float* so = slots_out + (size_t)b * (126 * 128);

#pragma unroll 1
    for (int t = 0; t < 126; ++t) {
        // ---- P1: conv + gelu -> feat ----
        {
            int o = tid & 31, ng = tid >> 5;
            const float* w = conv_w + o * 32;
            float acca = conv_b[o], accb = acca;
            const float* xa = &pool[P_X + ng * 36];
            const float* xb = &pool[P_X + (ng + 8) * 36];
#pragma unroll
            for (int k = 0; k < 32; k += 4) {
                float4 w4 = *(const float4*)&w[k];
                float4 a4 = *(const float4*)&xa[k];
                float4 b4 = *(const float4*)&xb[k];
                acca += w4.x * a4.x + w4.y * a4.y + w4.z * a4.z + w4.w * a4.w;
                accb += w4.x * b4.x + w4.y * b4.y + w4.z * b4.z + w4.w * b4.w;
            }
            pool[P_FEAT + ng * 36 + o] = fast_gelu(acca);
            pool[P_FEAT + (ng + 8) * 36 + o] = fast_gelu(accb);
        }
        __syncthreads();   // BAR 1

        // ---- P2: KQV GEMM + X(t+1) prefetch ----
        float4 pf;
        const bool havepf = (t < 125) && (tid < 128);
        if (havepf) {
            int h = tid >> 6, ll = tid & 63;
            int i = ll >> 2, j4 = ll & 3;
            pf = *(const float4*)&fb[(t + (h ? 1 : 2)) * 256 + i * 16 + j4 * 4];
        }
        {
            const int cg = tid & 63;
            const int wv = tid >> 6;
            const int col0 = cg * 2;
            float accx[4], accy[4];
#pragma unroll
            for (int j = 0; j < 4; ++j) { accx[j] = 0.f; accy[j] = 0.f; }
#pragma unroll
            for (int c = 0; c < 32; c += 4) {
                float2 a0 = *(const float2*)&pool[P_A12 + (c + 0) * 128 + col0];
                float2 a1 = *(const float2*)&pool[P_A12 + (c + 1) * 128 + col0];
                float2 a2 = *(const float2*)&pool[P_A12 + (c + 2) * 128 + col0];
                float2 a3 = *(const float2*)&pool[P_A12 + (c + 3) * 128 + col0];
#pragma unroll
                for (int j = 0; j < 4; ++j) {
                    float4 q = *(const float4*)&pool[P_FEAT + (wv * 4 + j) * 36 + c];
                    accx[j] += a0.x * q.x + a1.x * q.y + a2.x * q.z + a3.x * q.w;
                    accy[j] += a0.y * q.x + a1.y * q.y + a2.y * q.z + a3.y * q.w;
                }
            }
            float cx = pool[P_C12 + col0], cy = pool[P_C12 + col0 + 1];
#pragma unroll
            for (int j = 0; j < 4; ++j) {
                int n = wv * 4 + j;
                float vx = accx[j] + cx, vy = accy[j] + cy;
                if (col0 < 32) {
                    *(float2*)&pool[P_KQ + n * 36 + col0] = make_float2(vx, vy);
                } else {
                    pool[P_VWT + (col0 - 32) * 20 + n] = vx;
                    pool[P_VWT + (col0 - 31) * 20 + n] = vy;
                }
            }
        }
        if (havepf) {
            int h = tid >> 6, ll = tid & 63;
            int i = ll >> 2, j4 = ll & 3;
            int n = (i >> 2) * 4 + j4, p = i & 3;
            *(float4*)&pool[P_X + n * 36 + h * 16 + p * 4] = pf;
        }
        __syncthreads();   // BAR 2

        // ---- 3 attention iterations, 2 barriers each ----
#pragma unroll 1
        for (int it = 0; it < 3; ++it) {
            // phase A: wave0 logits + shfl-softmax ; waves1-3 gh
            if (wid == 0) {
                int s = lane >> 4, n = lane & 15;
                const float* sp = &pool[P_SLOTS + s * 36];
                const float* kp = &pool[P_KQ + n * 36];
                float acc = 0.f;
#pragma unroll
                for (int d = 0; d < 32; d += 4) {
                    float4 a = *(const float4*)&sp[d];
                    float4 c = *(const float4*)&kp[d];
                    acc += a.x * c.x + a.y * c.y + a.z * c.z + a.w * c.w;
                }
                float lg = acc * 0.17677669529663687f;  // 1/sqrt(32)
                float m = fmaxf(lg, __shfl_xor(lg, 16));
                m = fmaxf(m, __shfl_xor(m, 32));
                float e = __expf(lg - m);
                float ssum = e + __shfl_xor(e, 16);
                ssum += __shfl_xor(ssum, 32);
                pool[P_ATTN + s * 20 + n] = e / ssum;
            } else {
                int idx = tid - 64;
                int shh = idx / 96;
                int e = idx - shh * 96;
                int s0 = shh * 2;
                const float* w = &pool[P_WHH + e * 36];
                const float* sa = &pool[P_SLOTS + s0 * 36];
                const float* sb = &pool[P_SLOTS + (s0 + 1) * 36];
                float acc0 = pool[P_BHH + e], acc1 = acc0;
#pragma unroll
                for (int d = 0; d < 32; d += 4) {
                    float4 w4 = *(const float4*)&w[d];
                    float4 a4 = *(const float4*)&sa[d];
                    float4 b4 = *(const float4*)&sb[d];
                    acc0 += w4.x * a4.x + w4.y * a4.y + w4.z * a4.z + w4.w * a4.w;
                    acc1 += w4.x * b4.x + w4.y * b4.y + w4.z * b4.z + w4.w * b4.w;
                }
                pool[P_GH + s0 * 100 + e] = acc0;
                pool[P_GH + (s0 + 1) * 100 + e] = acc1;
            }
            __syncthreads();   // BAR A->B

            // phase B (merged gi + GRU combine): tid<128, (s,d)
            if (tid < 128) {
                int s = tid >> 5, d = tid & 31;
                float ar[16];
#pragma unroll
                for (int k = 0; k < 16; k += 4) {
                    float4 a4 = *(const float4*)&pool[P_ATTN + s * 20 + k];
                    ar[k] = a4.x; ar[k + 1] = a4.y; ar[k + 2] = a4.z; ar[k + 3] = a4.w;
                }
                const float* v0 = &pool[P_VWT + d * 20];
                const float* v1 = &pool[P_VWT + (d + 32) * 20];
                const float* v2 = &pool[P_VWT + (d + 64) * 20];
                float gir = pool[P_BIH + d];
                float giz = pool[P_BIH + 32 + d];
                float gin = pool[P_BIH + 64 + d];
#pragma unroll
                for (int n = 0; n < 16; n += 4) {
                    float4 x0 = *(const float4*)&v0[n];
                    float4 x1 = *(const float4*)&v1[n];
                    float4 x2 = *(const float4*)&v2[n];
                    gir += ar[n] * x0.x + ar[n + 1] * x0.y + ar[n + 2] * x0.z + ar[n + 3] * x0.w;
                    giz += ar[n] * x1.x + ar[n + 1] * x1.y + ar[n + 2] * x1.z + ar[n + 3] * x1.w;
                    gin += ar[n] * x2.x + ar[n + 1] * x2.y + ar[n + 2] * x2.z + ar[n + 3] * x2.w;
                }
                float ghr = pool[P_GH + s * 100 + d];
                float ghz = pool[P_GH + s * 100 + 32 + d];
                float ghn = pool[P_GH + s * 100 + 64 + d];
                float r = fast_sigmoid(gir + ghr);
                float z = fast_sigmoid(giz + ghz);
                float nn = fast_tanh(gin + r * ghn);
                float h = pool[P_SLOTS + s * 36 + d];
                float hn = (1.0f - z) * nn + z * h;
                pool[P_SLOTS + s * 36 + d] = hn;
                if (it == 2) so[t * 128 + tid] = hn;
            }
            __syncthreads();   // BAR B->next A
        }
    }
}

// ---------------------------------------------------------------------------
// Kernel B: batched decode (byte-identical to the verified ~223us version).
// GEMM (64512 x 512) = slots_traj (64512 x 128) @ dec_w^T, fused
// deconv(4x4,s4) + tanh + add curr + clip. 32 rows per block.
// ---------------------------------------------------------------------------
__global__ __launch_bounds__(TB, 1) void decode_kernel(
    const float* __restrict__ slots_traj, const float* __restrict__ frames,
    const float* __restrict__ dec_w, const float* __restrict__ dec_b,
    const float* __restrict__ deconv_w, const float* __restrict__ deconv_b,
    float* __restrict__ out)
{
    const int tid = threadIdx.x;
    const int m0 = blockIdx.x * 32;

    __shared__ float sl_s[32 * 132];
    __shared__ float wch_s[64 * 132];
    __shared__ float dw_s[512];
    __shared__ float db_s[512];

    for (int i = tid * 4; i < 32 * 128; i += TB * 4) {
        float4 v = *(const float4*)&slots_traj[(size_t)m0 * 128 + i];
        int r = i >> 7, k = i & 127;
        *(float4*)&sl_s[r * 132 + k] = v;
    }
    for (int i = tid; i < 512; i += TB) {
        dw_s[i] = deconv_w[i];
        db_s[i] = dec_b[i];
    }
    __syncthreads();

    const int cg = tid & 63;
    const int rg = tid >> 6;

    float acc[8][8];
#pragma unroll
    for (int ci = 0; ci < 8; ++ci)
#pragma unroll
        for (int rr = 0; rr < 8; ++rr) acc[ci][rr] = 0.f;

    const float* slb = &sl_s[(rg * 8) * 132];

#pragma unroll
    for (int ch = 0; ch < 8; ++ch) {
        for (int i = tid * 4; i < 64 * 128; i += TB * 4) {
            float4 v = *(const float4*)&dec_w[(size_t)ch * 8192 + i];
            int cl = i >> 7, k = i & 127;
            *(float4*)&wch_s[cl * 132 + k] = v;
        }
        __syncthreads();
        const float* wrow = &wch_s[cg * 132];
#pragma unroll 4
        for (int k = 0; k < 128; k += 4) {
            float4 w4 = *(const float4*)&wrow[k];
#pragma unroll
            for (int rr = 0; rr < 8; ++rr) {
                float4 s4 = *(const float4*)&slb[rr * 132 + k];
                acc[ch][rr] += w4.x * s4.x + w4.y * s4.y + w4.z * s4.z + w4.w * s4.w;
            }
        }
        __syncthreads();
    }

#pragma unroll
    for (int ci = 0; ci < 8; ++ci) {
        float bo = db_s[cg + 64 * ci];
#pragma unroll
        for (int rr = 0; rr < 8; ++rr) acc[ci][rr] += bo;
    }

    const int c0 = cg >> 4;
    const int sp = cg & 15;
    const int bi = sp >> 2, bj = sp & 3;
    const float db0 = deconv_b[0];

#pragma unroll 1
    for (int rr = 0; rr < 8; ++rr) {
        float part[16];
#pragma unroll
        for (int kl = 0; kl < 16; ++kl) part[kl] = 0.f;
#pragma unroll
        for (int m = 0; m < 8; ++m) {
            float sf = acc[m][rr];
            const float* dwp = &dw_s[(c0 + 4 * m) * 16];
#pragma unroll
            for (int kl = 0; kl < 16; ++kl) part[kl] += sf * dwp[kl];
        }
#pragma unroll
        for (int kl = 0; kl < 16; ++kl) {
            part[kl] += __shfl_xor(part[kl], 16);
            part[kl] += __shfl_xor(part[kl], 32);
        }
        if (c0 == 0) {
            int mrow = m0 + rg * 8 + rr;
            int bb = mrow / 126, tt = mrow - bb * 126;
            const float* fr = frames + ((size_t)bb * 128 + (tt + 1)) * 256;
            float* op = out + (size_t)mrow * 256;
#pragma unroll
            for (int kk = 0; kk < 4; ++kk) {
                int pixb = (bi * 4 + kk) * 16 + bj * 4;
                float4 c4 = *(const float4*)&fr[pixb];
                float4 o4;
                o4.x = fminf(fmaxf(c4.x + tanhf(part[kk * 4 + 0] + db0), 0.f), 1.f);
                o4.y = fminf(fmaxf(c4.y + tanhf(part[kk * 4 + 1] + db0), 0.f), 1.f);
                o4.z = fminf(fmaxf(c4.z + tanhf(part[kk * 4 + 2] + db0), 0.f), 1.f);
                o4.w = fminf(fmaxf(c4.w + tanhf(part[kk * 4 + 3] + db0), 0.f), 1.f);
                *(float4*)&op[pixb] = o4;
            }
        }
    }
}

extern "C" void kernel_launch(void* const* d_in, const int* in_sizes, int n_in,
                              void* d_out, int out_size, void* d_ws, size_t ws_size,
                              hipStream_t stream) {
    const float* frames    = (const float*)d_in[0];
    const float* slot_mu   = (const float*)d_in[1];
    const float* conv_w    = (const float*)d_in[2];
    const float* conv_b    = (const float*)d_in[3];
    const float* to_slot_w = (const float*)d_in[4];
    const float* to_slot_b = (const float*)d_in[5];
    const float* q_w       = (const float*)d_in[6];
    const float* k_w       = (const float*)d_in[7];
    const float* v_w       = (const float*)d_in[8];
    const float* gru_wih   = (const float*)d_in[9];
    const float* gru_whh   = (const float*)d_in[10];
    const float* gru_bih   = (const float*)d_in[11];
    const float* gru_bhh   = (const float*)d_in[12];
    const float* dec_w     = (const float*)d_in[13];
    const float* dec_b     = (const float*)d_in[14];
    const float* deconv_w  = (const float*)d_in[15];
    const float* deconv_b  = (const float*)d_in[16];

    float* slots_traj = (float*)d_ws;  // 512*126*128 floats = 33 MB
    float* outp = (float*)d_out;

    hipLaunchKernelGGL(slot_recur_kernel, dim3(512), dim3(256), 0, stream,
                       frames, slot_mu, conv_w, conv_b, to_slot_w, to_slot_b,
                       q_w, k_w, v_w, gru_wih, gru_whh, gru_bih, gru_bhh,
                       slots_traj);
    hipLaunchKernelGGL(decode_kernel, dim3(64512 / 32), dim3(TB), 0, stream,
                       slots_traj, frames, dec_w, dec_b, deconv_w, deconv_b,
                       outp);
}